// Round 3
// baseline (263.565 us; speedup 1.0000x reference)
//
#include <hip/hip_runtime.h>

#define ROW_T   8192
#define THREADS 512
#define ITEMS   16                    // elems per thread (4 x float4), 512*16 = 8192
#define NWAVES  (THREADS / 64)        // 8
#define RPB     4                     // rows per block, software-pipelined
#define EPSV    1e-4f

typedef float fvec4 __attribute__((ext_vector_type(4)));

// <=64 VGPR target -> 8 waves/SIMD -> 4 blocks/CU fully resident (grid 1024)
__global__ __launch_bounds__(THREADS, 8)
void cumnorm_kernel(const float* __restrict__ x, float* __restrict__ out) {
    __shared__ float wbs[2][NWAVES];   // parity-buffered wave totals
    __shared__ float wbss[2][NWAVES];

    const int t    = threadIdx.x;
    const int lane = t & 63;
    const int wid  = t >> 6;

    const float* __restrict__ xr   = x   + (long long)blockIdx.x * RPB * ROW_T;
    float* __restrict__       outr = out + (long long)blockIdx.x * RPB * ROW_T;

    const int e0 = t * ITEMS;

    // row 0 loads (only exposed latency; hidden by co-resident blocks)
    fvec4 c0 = *reinterpret_cast<const fvec4*>(xr + e0);
    fvec4 c1 = *reinterpret_cast<const fvec4*>(xr + e0 + 4);
    fvec4 c2 = *reinterpret_cast<const fvec4*>(xr + e0 + 8);
    fvec4 c3 = *reinterpret_cast<const fvec4*>(xr + e0 + 12);

    for (int r = 0; r < RPB; ++r) {
        // ---- prefetch row r+1 FIRST: loads fly under scan/barrier/normalize ----
        fvec4 n0, n1, n2, n3;
        if (r + 1 < RPB) {
            const float* nr = xr + (r + 1) * ROW_T + e0;
            n0 = *reinterpret_cast<const fvec4*>(nr);
            n1 = *reinterpret_cast<const fvec4*>(nr + 4);
            n2 = *reinterpret_cast<const fvec4*>(nr + 8);
            n3 = *reinterpret_cast<const fvec4*>(nr + 12);
        }

        // ---- thread-local (s, ss) over 16 consecutive elems ----
        float s = ((c0.x + c0.y) + (c0.z + c0.w)) + ((c1.x + c1.y) + (c1.z + c1.w))
                + ((c2.x + c2.y) + (c2.z + c2.w)) + ((c3.x + c3.y) + (c3.z + c3.w));
        float ss = fmaf(c0.x, c0.x, fmaf(c0.y, c0.y, fmaf(c0.z, c0.z, c0.w * c0.w)));
        ss = fmaf(c1.x, c1.x, fmaf(c1.y, c1.y, fmaf(c1.z, c1.z, fmaf(c1.w, c1.w, ss))));
        ss = fmaf(c2.x, c2.x, fmaf(c2.y, c2.y, fmaf(c2.z, c2.z, fmaf(c2.w, c2.w, ss))));
        ss = fmaf(c3.x, c3.x, fmaf(c3.y, c3.y, fmaf(c3.z, c3.z, fmaf(c3.w, c3.w, ss))));

        // ---- wave-wide inclusive scan of (s, ss) ----
        float is = s, iss = ss;
        #pragma unroll
        for (int off = 1; off < 64; off <<= 1) {
            const float us  = __shfl_up(is, off);
            const float uss = __shfl_up(iss, off);
            if (lane >= off) { is += us; iss += uss; }
        }
        if (lane == 63) { wbs[r & 1][wid] = is; wbss[r & 1][wid] = iss; }
        __syncthreads();               // single barrier per row (parity buffers)

        // ---- cross-wave exclusive prefix via 8-lane shfl mini-scan ----
        float a = wbs[r & 1][lane & (NWAVES - 1)];
        float b = wbss[r & 1][lane & (NWAVES - 1)];
        #pragma unroll
        for (int off = 1; off < NWAVES; off <<= 1) {
            const float ua = __shfl_up(a, off);
            const float ub = __shfl_up(b, off);
            if (lane >= off) { a += ua; b += ub; }
        }
        const float cs  = wid ? __shfl(a, wid - 1) : 0.f;
        const float css = wid ? __shfl(b, wid - 1) : 0.f;

        // exclusive prefix at this thread's first element
        float S  = cs  + (is  - s);
        float SS = css + (iss - ss);

        // ---- serial finish over own 16 elems, normalize, plain stores ----
        float* __restrict__ orow = outr + (long long)r * ROW_T + e0;
        fvec4 o;
#define CN_STEP(v, idx, dst) {                                            \
        S += (v); SS = fmaf((v), (v), SS);                                \
        const float inv  = __builtin_amdgcn_rcpf((float)(e0 + (idx) + 1));\
        const float mean = S * inv;                                       \
        const float var  = fmaf(SS, inv, -(mean * mean));                 \
        (dst) = ((v) - mean) * __builtin_amdgcn_rsqf(var + EPSV);         \
    }
        CN_STEP(c0.x,  0, o.x) CN_STEP(c0.y,  1, o.y)
        CN_STEP(c0.z,  2, o.z) CN_STEP(c0.w,  3, o.w)
        *reinterpret_cast<fvec4*>(orow) = o;
        CN_STEP(c1.x,  4, o.x) CN_STEP(c1.y,  5, o.y)
        CN_STEP(c1.z,  6, o.z) CN_STEP(c1.w,  7, o.w)
        *reinterpret_cast<fvec4*>(orow + 4) = o;
        CN_STEP(c2.x,  8, o.x) CN_STEP(c2.y,  9, o.y)
        CN_STEP(c2.z, 10, o.z) CN_STEP(c2.w, 11, o.w)
        *reinterpret_cast<fvec4*>(orow + 8) = o;
        CN_STEP(c3.x, 12, o.x) CN_STEP(c3.y, 13, o.y)
        CN_STEP(c3.z, 14, o.z) CN_STEP(c3.w, 15, o.w)
        *reinterpret_cast<fvec4*>(orow + 12) = o;
#undef CN_STEP

        // ---- rotate double-buffer (wait for prefetched loads lands HERE) ----
        if (r + 1 < RPB) { c0 = n0; c1 = n1; c2 = n2; c3 = n3; }
    }
}

extern "C" void kernel_launch(void* const* d_in, const int* in_sizes, int n_in,
                              void* d_out, int out_size, void* d_ws, size_t ws_size,
                              hipStream_t stream) {
    const float* x = (const float*)d_in[0];
    float* out = (float*)d_out;
    const int rows = out_size / ROW_T;        // 4096
    cumnorm_kernel<<<rows / RPB, THREADS, 0, stream>>>(x, out);
}

// Round 4
// 232.935 us; speedup vs baseline: 1.1315x; 1.1315x over previous
//
#include <hip/hip_runtime.h>

#define ROW_T   8192
#define THREADS 256
#define WPB     4                 // waves per block = rows per block (no inter-wave deps)
#define NT      32                // tiles per row, 256 elems (64 lanes x 4) each
#define PIPE    8                 // load pipeline depth (tiles in flight)
#define EPSV    1e-4f

typedef float fvec4 __attribute__((ext_vector_type(4)));

// One DPP-shifted add step of the classic GFX9 wave64 inclusive scan.
// Disabled/out-of-range lanes contribute 0 (old=0, bound_ctrl=true).
template<int CTRL, int RM>
__device__ __forceinline__ float dpp_add(float v) {
    const int p = __builtin_amdgcn_update_dpp(0, __float_as_int(v), CTRL, RM, 0xf, true);
    return v + __int_as_float(p);
}

// rocPRIM-style wave64 inclusive scan: 6 pure-VALU adds, no LDS pipe.
__device__ __forceinline__ float wave_incl_scan(float v) {
    v = dpp_add<0x111, 0xf>(v);   // row_shr:1
    v = dpp_add<0x112, 0xf>(v);   // row_shr:2
    v = dpp_add<0x114, 0xf>(v);   // row_shr:4
    v = dpp_add<0x118, 0xf>(v);   // row_shr:8  -> per-16-row inclusive
    v = dpp_add<0x142, 0xa>(v);   // row_bcast:15 -> rows 1,3
    v = dpp_add<0x143, 0xc>(v);   // row_bcast:31 -> rows 2,3
    return v;
}

// 4 waves/SIMD is the max residency 4096 waves allow; cap there (VGPR<=128, no spill risk)
__global__ __launch_bounds__(THREADS, 4)
void cumnorm_kernel(const float* __restrict__ x, float* __restrict__ out) {
    const int lane = threadIdx.x & 63;
    const int wid  = threadIdx.x >> 6;

    const long long row = (long long)blockIdx.x * WPB + wid;   // one wave <-> one row
    const float* __restrict__ xr   = x   + row * ROW_T;
    float* __restrict__       outr = out + row * ROW_T;
    const int l4 = lane * 4;

    // ---- 8-deep register load pipeline; dense 1KB per load instruction ----
    fvec4 B[PIPE];                       // fully unrolled -> static indices -> registers
    #pragma unroll
    for (int k = 0; k < PIPE; ++k)
        B[k] = *reinterpret_cast<const fvec4*>(xr + k * 256 + l4);

    float carry_s = 0.f, carry_ss = 0.f;

    #pragma unroll
    for (int k = 0; k < NT; ++k) {
        const fvec4 c = B[k & (PIPE - 1)];
        if (k + PIPE < NT)
            B[k & (PIPE - 1)] = *reinterpret_cast<const fvec4*>(xr + (k + PIPE) * 256 + l4);

        // ---- local (s, ss) over this lane's 4 consecutive elems ----
        float s  = (c.x + c.y) + (c.z + c.w);
        float ss = fmaf(c.x, c.x, fmaf(c.y, c.y, fmaf(c.z, c.z, c.w * c.w)));

        // ---- wave-wide inclusive scan (two independent DPP chains, ILP) ----
        const float is  = wave_incl_scan(s);
        const float iss = wave_incl_scan(ss);

        // exclusive prefix at this lane's first elem = tile carry + (is - s)
        float S  = carry_s  + (is  - s);
        float SS = carry_ss + (iss - ss);

        // row carry for next tile: lane 63 holds the tile total (SGPR broadcast)
        carry_s  += __int_as_float(__builtin_amdgcn_readlane(__float_as_int(is),  63));
        carry_ss += __int_as_float(__builtin_amdgcn_readlane(__float_as_int(iss), 63));

        // ---- serial finish over own 4 elems, normalize ----
        const int e0 = k * 256 + l4;
        fvec4 o;
#define CN_STEP(v, idx, dst) {                                            \
        S += (v); SS = fmaf((v), (v), SS);                                \
        const float inv  = __builtin_amdgcn_rcpf((float)(e0 + (idx) + 1));\
        const float mean = S * inv;                                       \
        const float var  = fmaf(SS, inv, -(mean * mean));                 \
        (dst) = ((v) - mean) * __builtin_amdgcn_rsqf(var + EPSV);         \
    }
        CN_STEP(c.x, 0, o.x)
        CN_STEP(c.y, 1, o.y)
        CN_STEP(c.z, 2, o.z)
        CN_STEP(c.w, 3, o.w)
#undef CN_STEP

        // dense 1KB store per instruction (proven: WRITE_SIZE == ideal)
        *reinterpret_cast<fvec4*>(outr + e0) = o;
    }
}

extern "C" void kernel_launch(void* const* d_in, const int* in_sizes, int n_in,
                              void* d_out, int out_size, void* d_ws, size_t ws_size,
                              hipStream_t stream) {
    const float* x = (const float*)d_in[0];
    float* out = (float*)d_out;
    const int rows = out_size / ROW_T;        // 4096
    cumnorm_kernel<<<rows / WPB, THREADS, 0, stream>>>(x, out);
}

// Round 5
// 232.603 us; speedup vs baseline: 1.1331x; 1.0014x over previous
//
#include <hip/hip_runtime.h>

#define ROW_T   8192
#define THREADS 256
#define WPB     4                 // waves per block = rows per block (independent waves)
#define NT      32                // tiles per row, 256 elems (64 lanes x 4) each
#define PIPE    8                 // load pipeline depth (tiles in flight)
#define EPSV    1e-4f

typedef float fvec4 __attribute__((ext_vector_type(4)));

// Scheduling fence: memory ops may NOT cross. Does not read any loaded value,
// so it pins load ISSUE position without hoisting the s_waitcnt to it.
#define MEMFENCE() asm volatile("" ::: "memory")

// One DPP-shifted add step of the classic GFX9 wave64 inclusive scan.
template<int CTRL, int RM>
__device__ __forceinline__ float dpp_add(float v) {
    const int p = __builtin_amdgcn_update_dpp(0, __float_as_int(v), CTRL, RM, 0xf, true);
    return v + __int_as_float(p);
}

// rocPRIM-style wave64 inclusive scan: 6 pure-VALU adds, no LDS pipe.
__device__ __forceinline__ float wave_incl_scan(float v) {
    v = dpp_add<0x111, 0xf>(v);   // row_shr:1
    v = dpp_add<0x112, 0xf>(v);   // row_shr:2
    v = dpp_add<0x114, 0xf>(v);   // row_shr:4
    v = dpp_add<0x118, 0xf>(v);   // row_shr:8  -> per-16-row inclusive
    v = dpp_add<0x142, 0xa>(v);   // row_bcast:15 -> rows 1,3
    v = dpp_add<0x143, 0xc>(v);   // row_bcast:31 -> rows 2,3
    return v;
}

// min 4 waves/EU -> VGPR cap 128: room for the 32-reg pipeline + ~40 working regs
__global__ __launch_bounds__(THREADS, 4)
void cumnorm_kernel(const float* __restrict__ x, float* __restrict__ out) {
    const int lane = threadIdx.x & 63;
    const int wid  = threadIdx.x >> 6;

    const long long row = (long long)blockIdx.x * WPB + wid;   // one wave <-> one row
    const float* __restrict__ xr   = x   + row * ROW_T;
    float* __restrict__       outr = out + row * ROW_T;
    const int l4 = lane * 4;

    // ---- prologue: fill the 8-deep register pipeline; dense 1KB per load ----
    fvec4 B[PIPE];                       // fully unrolled -> static indices -> registers
    #pragma unroll
    for (int k = 0; k < PIPE; ++k) {
        B[k] = *reinterpret_cast<const fvec4*>(xr + k * 256 + l4);
        MEMFENCE();                      // pin each load at issue order
    }

    float carry_s = 0.f, carry_ss = 0.f;

    #pragma unroll
    for (int k = 0; k < NT; ++k) {
        // consume slot first (register rename, free), THEN refill it and fence
        const fvec4 c = B[k & (PIPE - 1)];       // s_waitcnt for load k lands here
        if (k + PIPE < NT) {
            B[k & (PIPE - 1)] = *reinterpret_cast<const fvec4*>(xr + (k + PIPE) * 256 + l4);
        }
        MEMFENCE();                              // prefetch may not sink below this

        // ---- local (s, ss) over this lane's 4 consecutive elems ----
        float s  = (c.x + c.y) + (c.z + c.w);
        float ss = fmaf(c.x, c.x, fmaf(c.y, c.y, fmaf(c.z, c.z, c.w * c.w)));

        // ---- wave-wide inclusive scan (two independent DPP chains, ILP) ----
        const float is  = wave_incl_scan(s);
        const float iss = wave_incl_scan(ss);

        // exclusive prefix at this lane's first elem = tile carry + (is - s)
        float S  = carry_s  + (is  - s);
        float SS = carry_ss + (iss - ss);

        // row carry for next tile: lane 63 holds the tile total (SGPR broadcast)
        carry_s  += __int_as_float(__builtin_amdgcn_readlane(__float_as_int(is),  63));
        carry_ss += __int_as_float(__builtin_amdgcn_readlane(__float_as_int(iss), 63));

        // ---- serial finish over own 4 elems, normalize ----
        const int e0 = k * 256 + l4;
        fvec4 o;
#define CN_STEP(v, idx, dst) {                                            \
        S += (v); SS = fmaf((v), (v), SS);                                \
        const float inv  = __builtin_amdgcn_rcpf((float)(e0 + (idx) + 1));\
        const float mean = S * inv;                                       \
        const float var  = fmaf(SS, inv, -(mean * mean));                 \
        (dst) = ((v) - mean) * __builtin_amdgcn_rsqf(var + EPSV);         \
    }
        CN_STEP(c.x, 0, o.x)
        CN_STEP(c.y, 1, o.y)
        CN_STEP(c.z, 2, o.z)
        CN_STEP(c.w, 3, o.w)
#undef CN_STEP

        // dense 1KB store per instruction (proven: WRITE_SIZE == ideal)
        *reinterpret_cast<fvec4*>(outr + e0) = o;
        MEMFENCE();
    }
}

extern "C" void kernel_launch(void* const* d_in, const int* in_sizes, int n_in,
                              void* d_out, int out_size, void* d_ws, size_t ws_size,
                              hipStream_t stream) {
    const float* x = (const float*)d_in[0];
    float* out = (float*)d_out;
    const int rows = out_size / ROW_T;        // 4096
    cumnorm_kernel<<<rows / WPB, THREADS, 0, stream>>>(x, out);
}

// Round 6
// 232.204 us; speedup vs baseline: 1.1351x; 1.0017x over previous
//
#include <hip/hip_runtime.h>

#define ROW_T   8192
#define THREADS 256
#define WPB     4                 // waves per block = rows per block (independent waves)
#define NT      32                // tiles per row: 256 elems (64 lanes x float4) each
#define PIPE    12                // hand-built load pipeline depth (48 VGPRs of data)
#define EPSV    1e-4f

typedef float fvec4 __attribute__((ext_vector_type(4)));

// ---- DPP wave64 inclusive scan: 6 pure-VALU adds, no LDS pipe ----
template<int CTRL, int RM>
__device__ __forceinline__ float dpp_add(float v) {
    const int p = __builtin_amdgcn_update_dpp(0, __float_as_int(v), CTRL, RM, 0xf, true);
    return v + __int_as_float(p);
}
__device__ __forceinline__ float wave_incl_scan(float v) {
    v = dpp_add<0x111, 0xf>(v);   // row_shr:1
    v = dpp_add<0x112, 0xf>(v);   // row_shr:2
    v = dpp_add<0x114, 0xf>(v);   // row_shr:4
    v = dpp_add<0x118, 0xf>(v);   // row_shr:8
    v = dpp_add<0x142, 0xa>(v);   // row_bcast:15
    v = dpp_add<0x143, 0xc>(v);   // row_bcast:31
    return v;
}

// ---- prologue: fill the pipeline with hand-issued loads (fixed issue order) ----
template<int K>
__device__ __forceinline__ void prologue(const float* __restrict__ pa, fvec4 (&B)[PIPE]) {
    asm volatile("global_load_dwordx4 %0, %1, off" : "=v"(B[K]) : "v"(pa + K * 256));
    if constexpr (K + 1 < PIPE) prologue<K + 1>(pa, B);
}

// ---- one tile, fully unrolled via template recursion (all waits are literals) ----
template<int K>
__device__ __forceinline__ void tile(const float* __restrict__ pa,
                                     float* __restrict__ po,
                                     fvec4 (&B)[PIPE],
                                     float& carry_s, float& carry_ss, const int l4) {
    // Exact outstanding-op count at this wait (loads AND stores tick vmcnt, in order):
    // ops issued after L_K = loads L_{K+1}..L_{min(K+PIPE-1,NT-1)} + stores S_{max(0,K-PIPE)}..S_{K-1}
    constexpr int LOADS_AFTER  = (PIPE - 1) < (NT - 1 - K) ? (PIPE - 1) : (NT - 1 - K);
    constexpr int STORES_AFTER = (PIPE < K) ? PIPE : K;
    constexpr int N = LOADS_AFTER + STORES_AFTER;   // max 2*PIPE-1 = 23 <= 63

    asm volatile("s_waitcnt vmcnt(%0)" :: "i"(N));
    __builtin_amdgcn_sched_barrier(0);              // rule #18: consumers may not hoist

    const fvec4 c = B[K % PIPE];                    // copy out, then refill the slot

    if constexpr (K + PIPE < NT)
        asm volatile("global_load_dwordx4 %0, %1, off"
                     : "=v"(B[K % PIPE]) : "v"(pa + (K + PIPE) * 256));

    // ---- local (s, ss) over this lane's 4 consecutive elems ----
    float s  = (c.x + c.y) + (c.z + c.w);
    float ss = fmaf(c.x, c.x, fmaf(c.y, c.y, fmaf(c.z, c.z, c.w * c.w)));

    // ---- wave-wide inclusive scan (two independent DPP chains) ----
    const float is  = wave_incl_scan(s);
    const float iss = wave_incl_scan(ss);

    // exclusive prefix at this lane's first elem
    float S  = carry_s  + (is  - s);
    float SS = carry_ss + (iss - ss);

    // row carry: lane 63 holds the tile total (SGPR broadcast)
    carry_s  += __int_as_float(__builtin_amdgcn_readlane(__float_as_int(is),  63));
    carry_ss += __int_as_float(__builtin_amdgcn_readlane(__float_as_int(iss), 63));

    const int e0 = K * 256 + l4;
    fvec4 o;
#define CN_STEP(v, idx, dst) {                                            \
        S += (v); SS = fmaf((v), (v), SS);                                \
        const float inv  = __builtin_amdgcn_rcpf((float)(e0 + (idx) + 1));\
        const float mean = S * inv;                                       \
        const float var  = fmaf(SS, inv, -(mean * mean));                 \
        (dst) = ((v) - mean) * __builtin_amdgcn_rsqf(var + EPSV);         \
    }
    CN_STEP(c.x, 0, o.x)
    CN_STEP(c.y, 1, o.y)
    CN_STEP(c.z, 2, o.z)
    CN_STEP(c.w, 3, o.w)
#undef CN_STEP

    // hand-issued dense 1KB store (counts in vmcnt bookkeeping above)
    asm volatile("global_store_dwordx4 %0, %1, off" :: "v"(po + K * 256), "v"(o));

    if constexpr (K + 1 < NT) tile<K + 1>(pa, po, B, carry_s, carry_ss, l4);
}

__global__ __launch_bounds__(THREADS, 4)   // VGPR cap 128; ~80 expected
void cumnorm_kernel(const float* __restrict__ x, float* __restrict__ out) {
    const int lane = threadIdx.x & 63;
    const int wid  = threadIdx.x >> 6;

    const long long row = (long long)blockIdx.x * WPB + wid;   // one wave <-> one row
    const int l4 = lane * 4;
    const float* __restrict__ pa = x   + row * ROW_T + l4;
    float* __restrict__       po = out + row * ROW_T + l4;

    fvec4 B[PIPE];
    prologue<0>(pa, B);

    float carry_s = 0.f, carry_ss = 0.f;
    tile<0>(pa, po, B, carry_s, carry_ss, l4);

    asm volatile("s_waitcnt vmcnt(0)");   // drain stores before endpgm (cheap, safe)
}

extern "C" void kernel_launch(void* const* d_in, const int* in_sizes, int n_in,
                              void* d_out, int out_size, void* d_ws, size_t ws_size,
                              hipStream_t stream) {
    const float* x = (const float*)d_in[0];
    float* out = (float*)d_out;
    const int rows = out_size / ROW_T;        // 4096
    cumnorm_kernel<<<rows / WPB, THREADS, 0, stream>>>(x, out);
}

// Round 7
// 232.183 us; speedup vs baseline: 1.1352x; 1.0001x over previous
//
#include <hip/hip_runtime.h>

#define ROW_T   8192
#define THREADS 256
#define WPB     4                 // waves per block = rows per block (independent waves)
#define NT      32                // tiles per row: 256 elems (64 lanes x float4) each
#define D       8                 // LDS ring depth per wave (8 x 1KB slots)
#define SLOT_B  1024
#define EPSV    1e-4f

typedef float fvec4 __attribute__((ext_vector_type(4)));
typedef __attribute__((address_space(1))) const float glb_f;
typedef __attribute__((address_space(3))) float       lds_f;

// ---- DPP wave64 inclusive scan: 6 pure-VALU adds, no LDS pipe ----
template<int CTRL, int RM>
__device__ __forceinline__ float dpp_add(float v) {
    const int p = __builtin_amdgcn_update_dpp(0, __float_as_int(v), CTRL, RM, 0xf, true);
    return v + __int_as_float(p);
}
__device__ __forceinline__ float wave_incl_scan(float v) {
    v = dpp_add<0x111, 0xf>(v);   // row_shr:1
    v = dpp_add<0x112, 0xf>(v);   // row_shr:2
    v = dpp_add<0x114, 0xf>(v);   // row_shr:4
    v = dpp_add<0x118, 0xf>(v);   // row_shr:8
    v = dpp_add<0x142, 0xa>(v);   // row_bcast:15
    v = dpp_add<0x143, 0xc>(v);   // row_bcast:31
    return v;
}

// ---- prologue: fill the LDS ring with async loads (no VGPR destination!) ----
template<int K>
__device__ __forceinline__ void prologue_fill(const float* pa, const int lane, char* lwave) {
    __builtin_amdgcn_global_load_lds((glb_f*)(pa + K * 256 + lane * 4),
                                     (lds_f*)(lwave + K * SLOT_B), 16, 0, 0);
    if constexpr (K + 1 < D) prologue_fill<K + 1>(pa, lane, lwave);
}

// ---- one tile, fully unrolled; all waits are compile-time literals ----
template<int K>
__device__ __forceinline__ void tile(const float* pa, float* po, char* lwave,
                                     float& carry_s, float& carry_ss, const int lane) {
    // ops issued after load L_K (loads AND stores tick vmcnt, retire in order):
    // loads L_{K+1}..L_{min(K+D-1,NT-1)}  +  stores S_{max(0,K-D)}..S_{K-1}
    constexpr int LOADS_AFTER  = (D - 1) < (NT - 1 - K) ? (D - 1) : (NT - 1 - K);
    constexpr int STORES_AFTER = (K < D) ? K : D;
    constexpr int N = LOADS_AFTER + STORES_AFTER;    // max 2*D-1 = 15

    asm volatile("s_waitcnt vmcnt(%0)" :: "i"(N));
    __builtin_amdgcn_sched_barrier(0);               // rule #18: nothing hoists above

    // LDS byte offset of this wave's slot (AS3 cast -> 32-bit LDS offset)
    const unsigned loff = (unsigned)(unsigned long long)(lds_f*)(lwave + (K % D) * SLOT_B)
                        + (unsigned)lane * 16u;
    fvec4 c;
    asm volatile("ds_read_b128 %0, %1" : "=v"(c) : "v"(loff));
    asm volatile("s_waitcnt lgkmcnt(0)");
    __builtin_amdgcn_sched_barrier(0);               // data in c; slot now free

    // refill the freed slot D tiles ahead (async, no VGPR dest, stays in flight)
    if constexpr (K + D < NT)
        __builtin_amdgcn_global_load_lds((glb_f*)(pa + (K + D) * 256 + lane * 4),
                                         (lds_f*)(lwave + (K % D) * SLOT_B), 16, 0, 0);

    // ---- local (s, ss) over this lane's 4 consecutive elems ----
    float s  = (c.x + c.y) + (c.z + c.w);
    float ss = fmaf(c.x, c.x, fmaf(c.y, c.y, fmaf(c.z, c.z, c.w * c.w)));

    // ---- wave-wide inclusive scan (two independent DPP chains) ----
    const float is  = wave_incl_scan(s);
    const float iss = wave_incl_scan(ss);

    // exclusive prefix at this lane's first elem
    float S  = carry_s  + (is  - s);
    float SS = carry_ss + (iss - ss);

    // row carry: lane 63 holds the tile total (SGPR broadcast)
    carry_s  += __int_as_float(__builtin_amdgcn_readlane(__float_as_int(is),  63));
    carry_ss += __int_as_float(__builtin_amdgcn_readlane(__float_as_int(iss), 63));

    const int e0 = K * 256 + lane * 4;
    fvec4 o;
#define CN_STEP(v, idx, dst) {                                            \
        S += (v); SS = fmaf((v), (v), SS);                                \
        const float inv  = __builtin_amdgcn_rcpf((float)(e0 + (idx) + 1));\
        const float mean = S * inv;                                       \
        const float var  = fmaf(SS, inv, -(mean * mean));                 \
        (dst) = ((v) - mean) * __builtin_amdgcn_rsqf(var + EPSV);         \
    }
    CN_STEP(c.x, 0, o.x)
    CN_STEP(c.y, 1, o.y)
    CN_STEP(c.z, 2, o.z)
    CN_STEP(c.w, 3, o.w)
#undef CN_STEP

    // hand-issued dense 1KB store (pinned: it participates in vmcnt bookkeeping)
    asm volatile("global_store_dwordx4 %0, %1, off" :: "v"(po + K * 256), "v"(o));

    if constexpr (K + 1 < NT) tile<K + 1>(pa, po, lwave, carry_s, carry_ss, lane);
}

__global__ __launch_bounds__(THREADS, 4)   // 16 waves/CU, 4 blocks x 32KB LDS = 128KB/CU
void cumnorm_kernel(const float* __restrict__ x, float* __restrict__ out) {
    __shared__ char ldsbuf[WPB * D * SLOT_B];        // 32 KB

    const int lane = threadIdx.x & 63;
    const int wid  = threadIdx.x >> 6;

    const long long row = (long long)blockIdx.x * WPB + wid;   // one wave <-> one row
    const float* pa = x   + row * ROW_T;             // per-lane gaddr = pa + K*256 + lane*4
    float*       po = out + row * ROW_T + lane * 4;
    char* lwave = ldsbuf + wid * (D * SLOT_B);       // private 8KB ring per wave

    prologue_fill<0>(pa, lane, lwave);

    float carry_s = 0.f, carry_ss = 0.f;
    tile<0>(pa, po, lwave, carry_s, carry_ss, lane);

    asm volatile("s_waitcnt vmcnt(0)");              // drain stores before endpgm
}

extern "C" void kernel_launch(void* const* d_in, const int* in_sizes, int n_in,
                              void* d_out, int out_size, void* d_ws, size_t ws_size,
                              hipStream_t stream) {
    const float* x = (const float*)d_in[0];
    float* out = (float*)d_out;
    const int rows = out_size / ROW_T;        // 4096
    cumnorm_kernel<<<rows / WPB, THREADS, 0, stream>>>(x, out);
}